// Round 3
// baseline (266.788 us; speedup 1.0000x reference)
//
#include <hip/hip_runtime.h>
#include <stdint.h>

#define D_MODEL 1024
#define NHEAD 16
#define DKH 64
#define BATCH 4
#define SEQ 2048
#define M_ROWS (BATCH*SEQ)   // 8192
#define NBH (BATCH*NHEAD)    // 64

typedef float f32x4 __attribute__((ext_vector_type(4)));
typedef __bf16 bf16x8 __attribute__((ext_vector_type(8)));
typedef int int2v __attribute__((ext_vector_type(2)));
typedef int int4v __attribute__((ext_vector_type(4)));

__device__ __forceinline__ unsigned short f2bf(float x) {
    __bf16 b = (__bf16)x;                      // hardware v_cvt (RNE)
    return __builtin_bit_cast(unsigned short, b);
}

#define GLL(gsrc, ldst) \
    __builtin_amdgcn_global_load_lds((const __attribute__((address_space(1))) void*)(gsrc), \
                                     (__attribute__((address_space(3))) void*)(ldst), 16, 0, 0)

// ---------------------------------------------------------------------------
// Kernel 1: fp32 -> bf16 conversion / packing
// ---------------------------------------------------------------------------
__global__ __launch_bounds__(256) void k_convert(
    const float* __restrict__ z,  const float* __restrict__ wq,
    const float* __restrict__ wk, const float* __restrict__ wv,
    const float* __restrict__ wo,
    const float* __restrict__ bq, const float* __restrict__ bk,
    const float* __restrict__ bv,
    unsigned short* __restrict__ zb, unsigned short* __restrict__ wqkv,
    unsigned short* __restrict__ wob, float* __restrict__ biasf)
{
    int i = blockIdx.x * 256 + threadIdx.x;   // 0 .. 2097151
    {
        float4 v = ((const float4*)z)[i];
        ushort4 o; o.x = f2bf(v.x); o.y = f2bf(v.y); o.z = f2bf(v.z); o.w = f2bf(v.w);
        ((ushort4*)zb)[i] = o;
    }
    if (i < 262144) {   // 1048576/4 per weight matrix
        float4 v;
        ushort4 o;
        v = ((const float4*)wq)[i];
        o.x=f2bf(v.x); o.y=f2bf(v.y); o.z=f2bf(v.z); o.w=f2bf(v.w);
        ((ushort4*)wqkv)[i] = o;
        v = ((const float4*)wk)[i];
        o.x=f2bf(v.x); o.y=f2bf(v.y); o.z=f2bf(v.z); o.w=f2bf(v.w);
        ((ushort4*)wqkv)[262144 + i] = o;
        v = ((const float4*)wv)[i];
        o.x=f2bf(v.x); o.y=f2bf(v.y); o.z=f2bf(v.z); o.w=f2bf(v.w);
        ((ushort4*)wqkv)[524288 + i] = o;
        v = ((const float4*)wo)[i];
        o.x=f2bf(v.x); o.y=f2bf(v.y); o.z=f2bf(v.z); o.w=f2bf(v.w);
        ((ushort4*)wob)[i] = o;
    }
    if (i < 1024) {
        biasf[i]        = bq[i];
        biasf[1024 + i] = bk[i];
        biasf[2048 + i] = bv[i];
    }
}

// ---------------------------------------------------------------------------
// Kernel 2: QKV projection GEMM  C[8192,3072] = zb * wqkv^T + bias
// ---------------------------------------------------------------------------
__global__ __launch_bounds__(256) void k_gemm_qkv(
    const unsigned short* __restrict__ A,   // [8192][1024] bf16
    const unsigned short* __restrict__ Bw,  // [3072][1024] bf16
    const float* __restrict__ biasf,        // [3072]
    unsigned short* __restrict__ qb, unsigned short* __restrict__ kb,
    unsigned short* __restrict__ vtb)
{
    __shared__ unsigned short lds_a[128 * 32];
    __shared__ unsigned short lds_b[128 * 32];

    const int NT = 3072 / 128;  // 24
    int bid = blockIdx.x;
    int tn = bid % NT, tm = bid / NT;
    int m0 = tm * 128, n0 = tn * 128;
    int tid = threadIdx.x, wid = tid >> 6, lane = tid & 63;
    int wm = wid >> 1, wn = wid & 1;

    f32x4 acc[4][4] = {};

    int srow = lane >> 2;        // 0..15
    int scol = (lane & 3) * 8;   // element offset within 32-col row

    for (int kt = 0; kt < 32; ++kt) {
        int k0 = kt * 32;
#pragma unroll
        for (int i = 0; i < 2; ++i) {
            int rb = (wid * 2 + i) * 16;
            GLL(A  + (size_t)(m0 + rb + srow) * 1024 + k0 + scol, lds_a + rb * 32);
            GLL(Bw + (size_t)(n0 + rb + srow) * 1024 + k0 + scol, lds_b + rb * 32);
        }
        __syncthreads();
        bf16x8 af[4], bfr[4];
#pragma unroll
        for (int i = 0; i < 4; ++i)
            af[i] = *(const bf16x8*)(lds_a + (wm * 64 + i * 16 + (lane & 15)) * 32 + (lane >> 4) * 8);
#pragma unroll
        for (int j = 0; j < 4; ++j)
            bfr[j] = *(const bf16x8*)(lds_b + (wn * 64 + j * 16 + (lane & 15)) * 32 + (lane >> 4) * 8);
#pragma unroll
        for (int i = 0; i < 4; ++i)
#pragma unroll
            for (int j = 0; j < 4; ++j)
                acc[i][j] = __builtin_amdgcn_mfma_f32_16x16x32_bf16(af[i], bfr[j], acc[i][j], 0, 0, 0);
        __syncthreads();
    }

    int t = n0 >> 10;  // 0=Q 1=K 2=V
#pragma unroll
    for (int j = 0; j < 4; ++j) {
        int col = n0 + wn * 64 + j * 16 + (lane & 15);
        float bias = biasf[col];
        int d  = col & 1023;
        int h  = d >> 6;
        int dk = d & 63;
#pragma unroll
        for (int i = 0; i < 4; ++i) {
#pragma unroll
            for (int r = 0; r < 4; ++r) {
                int row = m0 + wm * 64 + i * 16 + (lane >> 4) * 4 + r;
                float v = acc[i][j][r] + bias;
                unsigned short bv16 = f2bf(v);
                int b_ = row >> 11, s_ = row & 2047;
                int bh = b_ * NHEAD + h;
                if (t == 0)      qb[((size_t)bh * SEQ + s_) * DKH + dk] = bv16;
                else if (t == 1) kb[((size_t)bh * SEQ + s_) * DKH + dk] = bv16;
                else             vtb[((size_t)bh * DKH + dk) * SEQ + s_] = bv16;
            }
        }
    }
}

// ---------------------------------------------------------------------------
// Kernel 3: flash attention.
//   S^T = mfma(K, Q) (cols = q, lane-local softmax).
//   P re-laid from S^T C-layout to O-MFMA A-frag via permlane32_swap +
//   shfl_xor(16) (cross-g, same-lq permute) -> PV uses full 16x16x32 MFMA
//   with conflict-free b128 V reads (same swizzled pattern as K reads).
// ---------------------------------------------------------------------------
__device__ __forceinline__ void stage_kv(
    const unsigned short* __restrict__ kb, const unsigned short* __restrict__ vtb,
    unsigned short* lk, unsigned short* lv,
    int bh, int t, int wid, int srow8, int sc)
{
#pragma unroll
    for (int i = 0; i < 2; ++i) {
        int rb = wid * 16 + i * 8;
        int row = rb + srow8;
        int cs = (sc ^ (row & 7)) * 8;   // inverse-swizzled global source chunk
        GLL(kb  + ((size_t)bh * SEQ + t * 64 + row) * DKH + cs, lk + rb * 64);
        GLL(vtb + ((size_t)bh * DKH + row) * SEQ + t * 64 + cs, lv + rb * 64);
    }
}

__global__ __launch_bounds__(256) void k_attn(
    const unsigned short* __restrict__ qg,
    const unsigned short* __restrict__ kb,
    const unsigned short* __restrict__ vtb,
    unsigned short* __restrict__ ctxb)
{
    __shared__ unsigned short lds_k[2][64 * 64];
    __shared__ unsigned short lds_v[2][64 * 64];

    int bid = blockIdx.x;
    // XCD-grouped swizzle: all 16 q-tiles of a (b,h) land on the same XCD.
    int x = bid & 7, li = bid >> 3;
    int bh = x * 8 + (li >> 4);
    int qt = li & 15;

    int tid = threadIdx.x, wid = tid >> 6, lane = tid & 63;
    int lq = lane & 15, g = lane >> 4;
    int srow8 = lane >> 3, sc = lane & 7;
    bool gOdd = (g & 1) != 0;

    // Q fragments: 2 q-sub-blocks x 2 k-halves, kept in registers
    bf16x8 aq[2][2];
    {
        const unsigned short* qp = qg + ((size_t)bh * SEQ + qt * 128 + wid * 32 + lq) * DKH + g * 8;
        aq[0][0] = *(const bf16x8*)(qp);
        aq[0][1] = *(const bf16x8*)(qp + 32);
        aq[1][0] = *(const bf16x8*)(qp + 16 * DKH);
        aq[1][1] = *(const bf16x8*)(qp + 16 * DKH + 32);
    }

    float m2[2]   = { -1e30f, -1e30f };
    float lsum[2] = { 0.f, 0.f };
    f32x4 oacc[2][4] = {};   // O layout: row q = 4g+r, col d = dj*16+lq

    const float SC = 0.125f;      // 1/sqrt(64)
    const float THR = 8.0f;       // defer-max threshold (T13)

    stage_kv(kb, vtb, &lds_k[0][0], &lds_v[0][0], bh, 0, wid, srow8, sc);

    for (int kt = 0; kt < 32; ++kt) {
        int cur = kt & 1;
        if (kt < 31) {
            stage_kv(kb, vtb, &lds_k[cur ^ 1][0], &lds_v[cur ^ 1][0], bh, kt + 1, wid, srow8, sc);
            asm volatile("s_waitcnt vmcnt(4)" ::: "memory");
        } else {
            asm volatile("s_waitcnt vmcnt(0)" ::: "memory");
        }
        __builtin_amdgcn_s_barrier();

        // ---- S^T = K Q^T : cols = q-row (lq), rows = kv jb*16 + 4g+r ----
        f32x4 st[2][4] = {};
#pragma unroll
        for (int kk = 0; kk < 2; ++kk) {
            bf16x8 kf[4];
#pragma unroll
            for (int jb = 0; jb < 4; ++jb) {
                int row = jb * 16 + lq;
                int c = kk * 4 + g;
                kf[jb] = *(const bf16x8*)(&lds_k[cur][row * 64 + ((c ^ (row & 7)) * 8)]);
            }
#pragma unroll
            for (int jb = 0; jb < 4; ++jb)
#pragma unroll
                for (int q = 0; q < 2; ++q)
                    st[q][jb] = __builtin_amdgcn_mfma_f32_16x16x32_bf16(kf[jb], aq[q][kk], st[q][jb], 0, 0, 0);
        }

        // ---- online softmax (columns are lane-local) ----
        float mt[2];
        bool need = false;
#pragma unroll
        for (int q = 0; q < 2; ++q) {
            float a0 = fmaxf(fmaxf(st[q][0][0], st[q][0][1]), fmaxf(st[q][0][2], st[q][0][3]));
            float a1 = fmaxf(fmaxf(st[q][1][0], st[q][1][1]), fmaxf(st[q][1][2], st[q][1][3]));
            float a2 = fmaxf(fmaxf(st[q][2][0], st[q][2][1]), fmaxf(st[q][2][2], st[q][2][3]));
            float a3 = fmaxf(fmaxf(st[q][3][0], st[q][3][1]), fmaxf(st[q][3][2], st[q][3][3]));
            float t0 = fmaxf(fmaxf(a0, a1), fmaxf(a2, a3));
            t0 = fmaxf(t0, __shfl_xor(t0, 16));
            t0 = fmaxf(t0, __shfl_xor(t0, 32));
            mt[q] = t0 * SC;
            need = need || (mt[q] > m2[q] + THR);
        }
        if (__any(need)) {
            float alpha[2];
#pragma unroll
            for (int q = 0; q < 2; ++q) {
                float mn = fmaxf(m2[q], mt[q]);
                alpha[q] = __expf(m2[q] - mn);
                m2[q] = mn;
                lsum[q] *= alpha[q];
            }
            // redistribute alpha (col-layout, q=lq) to O row-layout (q=4g+r)
#pragma unroll
            for (int q = 0; q < 2; ++q) {
                f32x4 ar;
#pragma unroll
                for (int r = 0; r < 4; ++r) ar[r] = __shfl(alpha[q], 4 * g + r);
#pragma unroll
                for (int dj = 0; dj < 4; ++dj) {
                    oacc[q][dj][0] *= ar[0]; oacc[q][dj][1] *= ar[1];
                    oacc[q][dj][2] *= ar[2]; oacc[q][dj][3] *= ar[3];
                }
            }
        }

        // ---- P = exp(S - m), packed as bf16 dword pairs, then l update ----
        unsigned int pk[2][4][2];
#pragma unroll
        for (int q = 0; q < 2; ++q) {
            float s = 0.f;
#pragma unroll
            for (int jb = 0; jb < 4; ++jb) {
                float p0 = __expf(st[q][jb][0] * SC - m2[q]);
                float p1 = __expf(st[q][jb][1] * SC - m2[q]);
                float p2 = __expf(st[q][jb][2] * SC - m2[q]);
                float p3 = __expf(st[q][jb][3] * SC - m2[q]);
                s += (p0 + p1) + (p2 + p3);
                pk[q][jb][0] = (unsigned int)f2bf(p0) | ((unsigned int)f2bf(p1) << 16);
                pk[q][jb][1] = (unsigned int)f2bf(p2) | ((unsigned int)f2bf(p3) << 16);
            }
            s += __shfl_xor(s, 16);
            s += __shfl_xor(s, 32);
            lsum[q] += s;
        }

        // ---- re-lay P: S^T C-layout -> A-frag (row=q=lq, k=g*8+0..7) ----
        bf16x8 paf[2][2];
#pragma unroll
        for (int q = 0; q < 2; ++q) {
#pragma unroll
            for (int kk = 0; kk < 2; ++kk) {
                int a0 = (int)pk[q][2 * kk][0],     a1 = (int)pk[q][2 * kk][1];
                int b0 = (int)pk[q][2 * kk + 1][0], b1 = (int)pk[q][2 * kk + 1][1];
                int2v r0 = __builtin_amdgcn_permlane32_swap(a0, b0, false, false);
                int2v r1 = __builtin_amdgcn_permlane32_swap(a1, b1, false, false);
                // keep own half, exchange the other across the g^1 16-group
                int c0 = gOdd ? r0[1] : r0[0];
                int c1 = gOdd ? r1[1] : r1[0];
                int e0 = gOdd ? r0[0] : r0[1];
                int e1 = gOdd ? r1[0] : r1[1];
                int s0 = __shfl_xor(e0, 16);
                int s1 = __shfl_xor(e1, 16);
                int4v ti;
                ti[0] = gOdd ? s0 : c0;
                ti[1] = gOdd ? s1 : c1;
                ti[2] = gOdd ? c0 : s0;
                ti[3] = gOdd ? c1 : s1;
                paf[q][kk] = __builtin_bit_cast(bf16x8, ti);
            }
        }

        // ---- O += P V  (16x16x32, conflict-free b128 V reads) ----
#pragma unroll
        for (int dj = 0; dj < 4; ++dj) {
            int row = dj * 16 + lq;
            int rx = row & 7;
#pragma unroll
            for (int kk = 0; kk < 2; ++kk) {
                bf16x8 vf = *(const bf16x8*)(&lds_v[cur][row * 64 + (((kk * 4 + g) ^ rx) * 8)]);
#pragma unroll
                for (int q = 0; q < 2; ++q)
                    oacc[q][dj] = __builtin_amdgcn_mfma_f32_16x16x32_bf16(paf[q][kk], vf, oacc[q][dj], 0, 0, 0);
            }
        }
        __builtin_amdgcn_s_barrier();
    }

    // ---- epilogue: ctx[b,s,h,dk] bf16; O rows q=4g+r, cols d=dj*16+lq ----
    int b_ = bh >> 4, h = bh & 15;
#pragma unroll
    for (int q = 0; q < 2; ++q) {
        f32x4 linv;
#pragma unroll
        for (int r = 0; r < 4; ++r) linv[r] = __shfl(lsum[q], 4 * g + r);
#pragma unroll
        for (int r = 0; r < 4; ++r) linv[r] = 1.0f / linv[r];
        int sbase = qt * 128 + wid * 32 + q * 16 + 4 * g;
#pragma unroll
        for (int dj = 0; dj < 4; ++dj) {
#pragma unroll
            for (int r = 0; r < 4; ++r) {
                int s_ = sbase + r;
                ctxb[(((size_t)b_ * SEQ + s_) * NHEAD + h) * DKH + dj * 16 + lq] =
                    f2bf(oacc[q][dj][r] * linv[r]);
            }
        }
    }
}

// ---------------------------------------------------------------------------
// Kernel 4: output projection  out[8192,1024] = ctxb * wob^T + bo  (fp32 out)
// ---------------------------------------------------------------------------
__global__ __launch_bounds__(256) void k_gemm_out(
    const unsigned short* __restrict__ A,    // ctxb [8192][1024] bf16
    const unsigned short* __restrict__ Bw,   // wob  [1024][1024] bf16
    const float* __restrict__ bo,
    float* __restrict__ out)
{
    __shared__ unsigned short lds_a[128 * 32];
    __shared__ unsigned short lds_b[128 * 32];

    const int NT = 1024 / 128;  // 8
    int bid = blockIdx.x;
    int tn = bid % NT, tm = bid / NT;
    int m0 = tm * 128, n0 = tn * 128;
    int tid = threadIdx.x, wid = tid >> 6, lane = tid & 63;
    int wm = wid >> 1, wn = wid & 1;

    f32x4 acc[4][4] = {};

    int srow = lane >> 2;
    int scol = (lane & 3) * 8;

    for (int kt = 0; kt < 32; ++kt) {
        int k0 = kt * 32;
#pragma unroll
        for (int i = 0; i < 2; ++i) {
            int rb = (wid * 2 + i) * 16;
            GLL(A  + (size_t)(m0 + rb + srow) * 1024 + k0 + scol, lds_a + rb * 32);
            GLL(Bw + (size_t)(n0 + rb + srow) * 1024 + k0 + scol, lds_b + rb * 32);
        }
        __syncthreads();
        bf16x8 af[4], bfr[4];
#pragma unroll
        for (int i = 0; i < 4; ++i)
            af[i] = *(const bf16x8*)(lds_a + (wm * 64 + i * 16 + (lane & 15)) * 32 + (lane >> 4) * 8);
#pragma unroll
        for (int j = 0; j < 4; ++j)
            bfr[j] = *(const bf16x8*)(lds_b + (wn * 64 + j * 16 + (lane & 15)) * 32 + (lane >> 4) * 8);
#pragma unroll
        for (int i = 0; i < 4; ++i)
#pragma unroll
            for (int j = 0; j < 4; ++j)
                acc[i][j] = __builtin_amdgcn_mfma_f32_16x16x32_bf16(af[i], bfr[j], acc[i][j], 0, 0, 0);
        __syncthreads();
    }

#pragma unroll
    for (int j = 0; j < 4; ++j) {
        int col = n0 + wn * 64 + j * 16 + (lane & 15);
        float bias = bo[col];
#pragma unroll
        for (int i = 0; i < 4; ++i) {
#pragma unroll
            for (int r = 0; r < 4; ++r) {
                int row = m0 + wm * 64 + i * 16 + (lane >> 4) * 4 + r;
                out[(size_t)row * 1024 + col] = acc[i][j][r] + bias;
            }
        }
    }
}

// ---------------------------------------------------------------------------
extern "C" void kernel_launch(void* const* d_in, const int* in_sizes, int n_in,
                              void* d_out, int out_size, void* d_ws, size_t ws_size,
                              hipStream_t stream)
{
    const float* z  = (const float*)d_in[0];
    const float* Wq = (const float*)d_in[1];
    const float* bq = (const float*)d_in[2];
    const float* Wk = (const float*)d_in[3];
    const float* bk = (const float*)d_in[4];
    const float* Wv = (const float*)d_in[5];
    const float* bv = (const float*)d_in[6];
    const float* Wo = (const float*)d_in[7];
    const float* bo = (const float*)d_in[8];
    float* out = (float*)d_out;

    char* ws = (char*)d_ws;
    unsigned short* zb   = (unsigned short*)(ws);                        // 16 MB
    unsigned short* ctxb = (unsigned short*)(ws);                        // 16 MB (reuse)
    unsigned short* wqkv = (unsigned short*)(ws + (16ull << 20));        //  6 MB
    unsigned short* wob  = (unsigned short*)(ws + (22ull << 20));        //  2 MB
    float*          biasf= (float*)(ws + (24ull << 20));                 // 12 KB
    unsigned short* qb   = (unsigned short*)(ws + (25ull << 20));        // 16 MB
    unsigned short* kb   = (unsigned short*)(ws + (41ull << 20));        // 16 MB
    unsigned short* vtb  = (unsigned short*)(ws + (57ull << 20));        // 16 MB -> 73 MB total

    k_convert<<<8192, 256, 0, stream>>>(z, Wq, Wk, Wv, Wo, bq, bk, bv, zb, wqkv, wob, biasf);
    k_gemm_qkv<<<64 * 24, 256, 0, stream>>>(zb, wqkv, biasf, qb, kb, vtb);
    k_attn<<<NBH * 16, 256, 0, stream>>>(qb, kb, vtb, ctxb);
    k_gemm_out<<<64 * 8, 256, 0, stream>>>(ctxb, wob, bo, out);
}

// Round 4
// 244.096 us; speedup vs baseline: 1.0930x; 1.0930x over previous
//
#include <hip/hip_runtime.h>
#include <stdint.h>

#define D_MODEL 1024
#define NHEAD 16
#define DKH 64
#define BATCH 4
#define SEQ 2048
#define M_ROWS (BATCH*SEQ)   // 8192
#define NBH (BATCH*NHEAD)    // 64

typedef float f32x4 __attribute__((ext_vector_type(4)));
typedef __bf16 bf16x8 __attribute__((ext_vector_type(8)));
typedef __bf16 bf16x4v __attribute__((ext_vector_type(4)));
typedef short short4v __attribute__((ext_vector_type(4)));

__device__ __forceinline__ unsigned short f2bf(float x) {
    __bf16 b = (__bf16)x;                      // hardware v_cvt (RNE)
    return __builtin_bit_cast(unsigned short, b);
}

#define GLL(gsrc, ldst) \
    __builtin_amdgcn_global_load_lds((const __attribute__((address_space(1))) void*)(gsrc), \
                                     (__attribute__((address_space(3))) void*)(ldst), 16, 0, 0)

// ---------------------------------------------------------------------------
// Kernel 1: fp32 -> bf16 conversion / packing
// ---------------------------------------------------------------------------
__global__ __launch_bounds__(256) void k_convert(
    const float* __restrict__ z,  const float* __restrict__ wq,
    const float* __restrict__ wk, const float* __restrict__ wv,
    const float* __restrict__ wo,
    const float* __restrict__ bq, const float* __restrict__ bk,
    const float* __restrict__ bv,
    unsigned short* __restrict__ zb, unsigned short* __restrict__ wqkv,
    unsigned short* __restrict__ wob, float* __restrict__ biasf)
{
    int i = blockIdx.x * 256 + threadIdx.x;   // 0 .. 2097151
    {
        float4 v = ((const float4*)z)[i];
        ushort4 o; o.x = f2bf(v.x); o.y = f2bf(v.y); o.z = f2bf(v.z); o.w = f2bf(v.w);
        ((ushort4*)zb)[i] = o;
    }
    if (i < 262144) {   // 1048576/4 per weight matrix
        float4 v;
        ushort4 o;
        v = ((const float4*)wq)[i];
        o.x=f2bf(v.x); o.y=f2bf(v.y); o.z=f2bf(v.z); o.w=f2bf(v.w);
        ((ushort4*)wqkv)[i] = o;
        v = ((const float4*)wk)[i];
        o.x=f2bf(v.x); o.y=f2bf(v.y); o.z=f2bf(v.z); o.w=f2bf(v.w);
        ((ushort4*)wqkv)[262144 + i] = o;
        v = ((const float4*)wv)[i];
        o.x=f2bf(v.x); o.y=f2bf(v.y); o.z=f2bf(v.z); o.w=f2bf(v.w);
        ((ushort4*)wqkv)[524288 + i] = o;
        v = ((const float4*)wo)[i];
        o.x=f2bf(v.x); o.y=f2bf(v.y); o.z=f2bf(v.z); o.w=f2bf(v.w);
        ((ushort4*)wob)[i] = o;
    }
    if (i < 1024) {
        biasf[i]        = bq[i];
        biasf[1024 + i] = bk[i];
        biasf[2048 + i] = bv[i];
    }
}

// ---------------------------------------------------------------------------
// Kernel 2: QKV projection GEMM  C[8192,3072] = zb * wqkv^T + bias
// Q is pre-scaled by log2(e)/8 (softmax scale folded, log2 domain) so the
// attention kernel can use raw v_exp_f32 (2^x) with no per-element mul/sub.
// ---------------------------------------------------------------------------
__global__ __launch_bounds__(256) void k_gemm_qkv(
    const unsigned short* __restrict__ A,   // [8192][1024] bf16
    const unsigned short* __restrict__ Bw,  // [3072][1024] bf16
    const float* __restrict__ biasf,        // [3072]
    unsigned short* __restrict__ qb, unsigned short* __restrict__ kb,
    unsigned short* __restrict__ vtb)
{
    __shared__ unsigned short lds_a[128 * 32];
    __shared__ unsigned short lds_b[128 * 32];

    const int NT = 3072 / 128;  // 24
    int bid = blockIdx.x;
    int tn = bid % NT, tm = bid / NT;
    int m0 = tm * 128, n0 = tn * 128;
    int tid = threadIdx.x, wid = tid >> 6, lane = tid & 63;
    int wm = wid >> 1, wn = wid & 1;

    f32x4 acc[4][4] = {};

    int srow = lane >> 2;        // 0..15
    int scol = (lane & 3) * 8;   // element offset within 32-col row

    for (int kt = 0; kt < 32; ++kt) {
        int k0 = kt * 32;
#pragma unroll
        for (int i = 0; i < 2; ++i) {
            int rb = (wid * 2 + i) * 16;
            GLL(A  + (size_t)(m0 + rb + srow) * 1024 + k0 + scol, lds_a + rb * 32);
            GLL(Bw + (size_t)(n0 + rb + srow) * 1024 + k0 + scol, lds_b + rb * 32);
        }
        __syncthreads();
        bf16x8 af[4], bfr[4];
#pragma unroll
        for (int i = 0; i < 4; ++i)
            af[i] = *(const bf16x8*)(lds_a + (wm * 64 + i * 16 + (lane & 15)) * 32 + (lane >> 4) * 8);
#pragma unroll
        for (int j = 0; j < 4; ++j)
            bfr[j] = *(const bf16x8*)(lds_b + (wn * 64 + j * 16 + (lane & 15)) * 32 + (lane >> 4) * 8);
#pragma unroll
        for (int i = 0; i < 4; ++i)
#pragma unroll
            for (int j = 0; j < 4; ++j)
                acc[i][j] = __builtin_amdgcn_mfma_f32_16x16x32_bf16(af[i], bfr[j], acc[i][j], 0, 0, 0);
        __syncthreads();
    }

    const float QSC = 0.18033688011112042f;  // log2(e) / sqrt(64)
    int t = n0 >> 10;  // 0=Q 1=K 2=V
#pragma unroll
    for (int j = 0; j < 4; ++j) {
        int col = n0 + wn * 64 + j * 16 + (lane & 15);
        float bias = biasf[col];
        int d  = col & 1023;
        int h  = d >> 6;
        int dk = d & 63;
#pragma unroll
        for (int i = 0; i < 4; ++i) {
#pragma unroll
            for (int r = 0; r < 4; ++r) {
                int row = m0 + wm * 64 + i * 16 + (lane >> 4) * 4 + r;
                float v = acc[i][j][r] + bias;
                if (t == 0) v *= QSC;            // uniform per block
                unsigned short bv16 = f2bf(v);
                int b_ = row >> 11, s_ = row & 2047;
                int bh = b_ * NHEAD + h;
                if (t == 0)      qb[((size_t)bh * SEQ + s_) * DKH + dk] = bv16;
                else if (t == 1) kb[((size_t)bh * SEQ + s_) * DKH + dk] = bv16;
                else             vtb[((size_t)bh * DKH + dk) * SEQ + s_] = bv16;
            }
        }
    }
}

// ---------------------------------------------------------------------------
// Kernel 3: flash attention, no-max unnormalized softmax.
//   S^T = mfma(K, Qscaled)  (cols = q, already in log2 domain)
//   P   = v_exp_f32(S^T)    (unnormalized; 2^-M constant cancels in PV/l)
//   P's C-layout IS the B-frag of mfma_16x16x16bf16_1k -> PV direct from
//   registers, zero repack, zero cross-lane per tile.
//   lsum accumulated per-lane; single shfl_xor(16)+(32) reduce at block end.
// ---------------------------------------------------------------------------
__device__ __forceinline__ void stage_kv(
    const unsigned short* __restrict__ kb, const unsigned short* __restrict__ vtb,
    unsigned short* lk, unsigned short* lv,
    int bh, int t, int wid, int srow8, int sc)
{
#pragma unroll
    for (int i = 0; i < 2; ++i) {
        int rb = wid * 16 + i * 8;
        int row = rb + srow8;
        int cs = (sc ^ (row & 7)) * 8;   // inverse-swizzled global source chunk
        GLL(kb  + ((size_t)bh * SEQ + t * 64 + row) * DKH + cs, lk + rb * 64);
        GLL(vtb + ((size_t)bh * DKH + row) * SEQ + t * 64 + cs, lv + rb * 64);
    }
}

__global__ __launch_bounds__(256) void k_attn(
    const unsigned short* __restrict__ qg,
    const unsigned short* __restrict__ kb,
    const unsigned short* __restrict__ vtb,
    unsigned short* __restrict__ ctxb)
{
    __shared__ unsigned short lds_k[2][64 * 64];
    __shared__ unsigned short lds_v[2][64 * 64];

    int bid = blockIdx.x;
    // XCD-grouped swizzle: all 16 q-tiles of a (b,h) land on the same XCD.
    int x = bid & 7, li = bid >> 3;
    int bh = x * 8 + (li >> 4);
    int qt = li & 15;

    int tid = threadIdx.x, wid = tid >> 6, lane = tid & 63;
    int lq = lane & 15, g = lane >> 4;
    int srow8 = lane >> 3, sc = lane & 7;

    // Q fragments: 2 q-sub-blocks x 2 k-halves, kept in registers
    bf16x8 aq[2][2];
    {
        const unsigned short* qp = qg + ((size_t)bh * SEQ + qt * 128 + wid * 32 + lq) * DKH + g * 8;
        aq[0][0] = *(const bf16x8*)(qp);
        aq[0][1] = *(const bf16x8*)(qp + 32);
        aq[1][0] = *(const bf16x8*)(qp + 16 * DKH);
        aq[1][1] = *(const bf16x8*)(qp + 16 * DKH + 32);
    }

    float lsum[2] = { 0.f, 0.f };
    f32x4 oacc[2][4] = {};   // O^T layout: row d = 4g+r (per dj block), col q = lq

    stage_kv(kb, vtb, &lds_k[0][0], &lds_v[0][0], bh, 0, wid, srow8, sc);

    for (int kt = 0; kt < 32; ++kt) {
        int cur = kt & 1;
        if (kt < 31) {
            stage_kv(kb, vtb, &lds_k[cur ^ 1][0], &lds_v[cur ^ 1][0], bh, kt + 1, wid, srow8, sc);
            asm volatile("s_waitcnt vmcnt(4)" ::: "memory");
        } else {
            asm volatile("s_waitcnt vmcnt(0)" ::: "memory");
        }
        __builtin_amdgcn_s_barrier();

        // ---- S^T = K Q^T : cols = q-row (lq), rows = kv jb*16 + 4g+r ----
        f32x4 st[2][4] = {};
#pragma unroll
        for (int kk = 0; kk < 2; ++kk) {
            bf16x8 kf[4];
#pragma unroll
            for (int jb = 0; jb < 4; ++jb) {
                int row = jb * 16 + lq;
                int c = kk * 4 + g;
                kf[jb] = *(const bf16x8*)(&lds_k[cur][row * 64 + ((c ^ (row & 7)) * 8)]);
            }
#pragma unroll
            for (int jb = 0; jb < 4; ++jb)
#pragma unroll
                for (int q = 0; q < 2; ++q)
                    st[q][jb] = __builtin_amdgcn_mfma_f32_16x16x32_bf16(kf[jb], aq[q][kk], st[q][jb], 0, 0, 0);
        }

        // ---- P = 2^(S^T) unnormalized; lsum per-lane; pack B-frags ----
        short4v w[2][4];
#pragma unroll
        for (int q = 0; q < 2; ++q) {
#pragma unroll
            for (int jb = 0; jb < 4; ++jb) {
                float p0 = __builtin_amdgcn_exp2f(st[q][jb][0]);
                float p1 = __builtin_amdgcn_exp2f(st[q][jb][1]);
                float p2 = __builtin_amdgcn_exp2f(st[q][jb][2]);
                float p3 = __builtin_amdgcn_exp2f(st[q][jb][3]);
                lsum[q] += (p0 + p1) + (p2 + p3);
                bf16x4v pb;
                pb[0] = (__bf16)p0; pb[1] = (__bf16)p1; pb[2] = (__bf16)p2; pb[3] = (__bf16)p3;
                w[q][jb] = __builtin_bit_cast(short4v, pb);
            }
        }

        // ---- O^T += V^T @ P  (16x16x16, B-frag = P C-layout, no exchange) ----
#pragma unroll
        for (int dj = 0; dj < 4; ++dj) {
            int row = dj * 16 + lq;
            int rx = row & 7;
#pragma unroll
            for (int jb = 0; jb < 4; ++jb) {
                int c = jb * 2 + (g >> 1);
                short4v vf = *(const short4v*)(&lds_v[cur][row * 64 + ((c ^ rx) * 8) + (g & 1) * 4]);
#pragma unroll
                for (int q = 0; q < 2; ++q)
                    oacc[q][dj] = __builtin_amdgcn_mfma_f32_16x16x16bf16_1k(vf, w[q][jb], oacc[q][dj], 0, 0, 0);
            }
        }
        __builtin_amdgcn_s_barrier();
    }

    // ---- epilogue: reduce lsum across g-groups, write ctx[b,s,h,dk] ----
    int b_ = bh >> 4, h = bh & 15;
#pragma unroll
    for (int q = 0; q < 2; ++q) {
        float s = lsum[q];
        s += __shfl_xor(s, 16);
        s += __shfl_xor(s, 32);
        float inv = 1.0f / s;
        int s_ = qt * 128 + wid * 32 + q * 16 + lq;
        unsigned short* op = ctxb + (((size_t)b_ * SEQ + s_) * NHEAD + h) * DKH;
#pragma unroll
        for (int dj = 0; dj < 4; ++dj) {
#pragma unroll
            for (int t = 0; t < 2; ++t) {
                unsigned short e0 = f2bf(oacc[q][dj][2 * t]     * inv);
                unsigned short e1 = f2bf(oacc[q][dj][2 * t + 1] * inv);
                unsigned int u = ((unsigned int)e1 << 16) | (unsigned int)e0;
                *(unsigned int*)(op + dj * 16 + 4 * g + 2 * t) = u;
            }
        }
    }
}

// ---------------------------------------------------------------------------
// Kernel 4: output projection  out[8192,1024] = ctxb * wob^T + bo  (fp32 out)
// ---------------------------------------------------------------------------
__global__ __launch_bounds__(256) void k_gemm_out(
    const unsigned short* __restrict__ A,    // ctxb [8192][1024] bf16
    const unsigned short* __restrict__ Bw,   // wob  [1024][1024] bf16
    const float* __restrict__ bo,
    float* __restrict__ out)
{
    __shared__ unsigned short lds_a[128 * 32];
    __shared__ unsigned short lds_b[128 * 32];

    const int NT = 1024 / 128;  // 8
    int bid = blockIdx.x;
    int tn = bid % NT, tm = bid / NT;
    int m0 = tm * 128, n0 = tn * 128;
    int tid = threadIdx.x, wid = tid >> 6, lane = tid & 63;
    int wm = wid >> 1, wn = wid & 1;

    f32x4 acc[4][4] = {};

    int srow = lane >> 2;
    int scol = (lane & 3) * 8;

    for (int kt = 0; kt < 32; ++kt) {
        int k0 = kt * 32;
#pragma unroll
        for (int i = 0; i < 2; ++i) {
            int rb = (wid * 2 + i) * 16;
            GLL(A  + (size_t)(m0 + rb + srow) * 1024 + k0 + scol, lds_a + rb * 32);
            GLL(Bw + (size_t)(n0 + rb + srow) * 1024 + k0 + scol, lds_b + rb * 32);
        }
        __syncthreads();
        bf16x8 af[4], bfr[4];
#pragma unroll
        for (int i = 0; i < 4; ++i)
            af[i] = *(const bf16x8*)(lds_a + (wm * 64 + i * 16 + (lane & 15)) * 32 + (lane >> 4) * 8);
#pragma unroll
        for (int j = 0; j < 4; ++j)
            bfr[j] = *(const bf16x8*)(lds_b + (wn * 64 + j * 16 + (lane & 15)) * 32 + (lane >> 4) * 8);
#pragma unroll
        for (int i = 0; i < 4; ++i)
#pragma unroll
            for (int j = 0; j < 4; ++j)
                acc[i][j] = __builtin_amdgcn_mfma_f32_16x16x32_bf16(af[i], bfr[j], acc[i][j], 0, 0, 0);
        __syncthreads();
    }

#pragma unroll
    for (int j = 0; j < 4; ++j) {
        int col = n0 + wn * 64 + j * 16 + (lane & 15);
        float bias = bo[col];
#pragma unroll
        for (int i = 0; i < 4; ++i) {
#pragma unroll
            for (int r = 0; r < 4; ++r) {
                int row = m0 + wm * 64 + i * 16 + (lane >> 4) * 4 + r;
                out[(size_t)row * 1024 + col] = acc[i][j][r] + bias;
            }
        }
    }
}

// ---------------------------------------------------------------------------
extern "C" void kernel_launch(void* const* d_in, const int* in_sizes, int n_in,
                              void* d_out, int out_size, void* d_ws, size_t ws_size,
                              hipStream_t stream)
{
    const float* z  = (const float*)d_in[0];
    const float* Wq = (const float*)d_in[1];
    const float* bq = (const float*)d_in[2];
    const float* Wk = (const float*)d_in[3];
    const float* bk = (const float*)d_in[4];
    const float* Wv = (const float*)d_in[5];
    const float* bv = (const float*)d_in[6];
    const float* Wo = (const float*)d_in[7];
    const float* bo = (const float*)d_in[8];
    float* out = (float*)d_out;

    char* ws = (char*)d_ws;
    unsigned short* zb   = (unsigned short*)(ws);                        // 16 MB
    unsigned short* ctxb = (unsigned short*)(ws);                        // 16 MB (reuse)
    unsigned short* wqkv = (unsigned short*)(ws + (16ull << 20));        //  6 MB
    unsigned short* wob  = (unsigned short*)(ws + (22ull << 20));        //  2 MB
    float*          biasf= (float*)(ws + (24ull << 20));                 // 12 KB
    unsigned short* qb   = (unsigned short*)(ws + (25ull << 20));        // 16 MB
    unsigned short* kb   = (unsigned short*)(ws + (41ull << 20));        // 16 MB
    unsigned short* vtb  = (unsigned short*)(ws + (57ull << 20));        // 16 MB -> 73 MB total

    k_convert<<<8192, 256, 0, stream>>>(z, Wq, Wk, Wv, Wo, bq, bk, bv, zb, wqkv, wob, biasf);
    k_gemm_qkv<<<64 * 24, 256, 0, stream>>>(zb, wqkv, biasf, qb, kb, vtb);
    k_attn<<<NBH * 16, 256, 0, stream>>>(qb, kb, vtb, ctxb);
    k_gemm_out<<<64 * 8, 256, 0, stream>>>(ctxb, wob, bo, out);
}

// Round 5
// 239.359 us; speedup vs baseline: 1.1146x; 1.0198x over previous
//
#include <hip/hip_runtime.h>
#include <stdint.h>

#define D_MODEL 1024
#define NHEAD 16
#define DKH 64
#define BATCH 4
#define SEQ 2048
#define M_ROWS (BATCH*SEQ)   // 8192
#define NBH (BATCH*NHEAD)    // 64

typedef float f32x4 __attribute__((ext_vector_type(4)));
typedef __bf16 bf16x8 __attribute__((ext_vector_type(8)));
typedef __bf16 bf16x4v __attribute__((ext_vector_type(4)));
typedef short short4v __attribute__((ext_vector_type(4)));
typedef int int2v __attribute__((ext_vector_type(2)));
typedef int int4v __attribute__((ext_vector_type(4)));

__device__ __forceinline__ unsigned short f2bf(float x) {
    __bf16 b = (__bf16)x;                      // hardware v_cvt (RNE)
    return __builtin_bit_cast(unsigned short, b);
}

#define GLL(gsrc, ldst) \
    __builtin_amdgcn_global_load_lds((const __attribute__((address_space(1))) void*)(gsrc), \
                                     (__attribute__((address_space(3))) void*)(ldst), 16, 0, 0)

// ---------------------------------------------------------------------------
// Kernel 1: fp32 -> bf16 conversion / packing
// ---------------------------------------------------------------------------
__global__ __launch_bounds__(256) void k_convert(
    const float* __restrict__ z,  const float* __restrict__ wq,
    const float* __restrict__ wk, const float* __restrict__ wv,
    const float* __restrict__ wo,
    const float* __restrict__ bq, const float* __restrict__ bk,
    const float* __restrict__ bv,
    unsigned short* __restrict__ zb, unsigned short* __restrict__ wqkv,
    unsigned short* __restrict__ wob, float* __restrict__ biasf)
{
    int i = blockIdx.x * 256 + threadIdx.x;   // 0 .. 2097151
    {
        float4 v = ((const float4*)z)[i];
        ushort4 o; o.x = f2bf(v.x); o.y = f2bf(v.y); o.z = f2bf(v.z); o.w = f2bf(v.w);
        ((ushort4*)zb)[i] = o;
    }
    if (i < 262144) {   // 1048576/4 per weight matrix
        float4 v;
        ushort4 o;
        v = ((const float4*)wq)[i];
        o.x=f2bf(v.x); o.y=f2bf(v.y); o.z=f2bf(v.z); o.w=f2bf(v.w);
        ((ushort4*)wqkv)[i] = o;
        v = ((const float4*)wk)[i];
        o.x=f2bf(v.x); o.y=f2bf(v.y); o.z=f2bf(v.z); o.w=f2bf(v.w);
        ((ushort4*)wqkv)[262144 + i] = o;
        v = ((const float4*)wv)[i];
        o.x=f2bf(v.x); o.y=f2bf(v.y); o.z=f2bf(v.z); o.w=f2bf(v.w);
        ((ushort4*)wqkv)[524288 + i] = o;
        v = ((const float4*)wo)[i];
        o.x=f2bf(v.x); o.y=f2bf(v.y); o.z=f2bf(v.z); o.w=f2bf(v.w);
        ((ushort4*)wob)[i] = o;
    }
    if (i < 1024) {
        biasf[i]        = bq[i];
        biasf[1024 + i] = bk[i];
        biasf[2048 + i] = bv[i];
    }
}

// ---------------------------------------------------------------------------
// Kernel 2: QKV projection GEMM  C[8192,3072] = zb * wqkv^T + bias
// Q is pre-scaled by log2(e)/8 (softmax scale folded, log2 domain) so the
// attention kernel can use raw v_exp_f32 (2^x) with no per-element mul/sub.
// ---------------------------------------------------------------------------
__global__ __launch_bounds__(256) void k_gemm_qkv(
    const unsigned short* __restrict__ A,   // [8192][1024] bf16
    const unsigned short* __restrict__ Bw,  // [3072][1024] bf16
    const float* __restrict__ biasf,        // [3072]
    unsigned short* __restrict__ qb, unsigned short* __restrict__ kb,
    unsigned short* __restrict__ vtb)
{
    __shared__ unsigned short lds_a[128 * 32];
    __shared__ unsigned short lds_b[128 * 32];

    const int NT = 3072 / 128;  // 24
    int bid = blockIdx.x;
    int tn = bid % NT, tm = bid / NT;
    int m0 = tm * 128, n0 = tn * 128;
    int tid = threadIdx.x, wid = tid >> 6, lane = tid & 63;
    int wm = wid >> 1, wn = wid & 1;

    f32x4 acc[4][4] = {};

    int srow = lane >> 2;        // 0..15
    int scol = (lane & 3) * 8;   // element offset within 32-col row

    for (int kt = 0; kt < 32; ++kt) {
        int k0 = kt * 32;
#pragma unroll
        for (int i = 0; i < 2; ++i) {
            int rb = (wid * 2 + i) * 16;
            GLL(A  + (size_t)(m0 + rb + srow) * 1024 + k0 + scol, lds_a + rb * 32);
            GLL(Bw + (size_t)(n0 + rb + srow) * 1024 + k0 + scol, lds_b + rb * 32);
        }
        __syncthreads();
        bf16x8 af[4], bfr[4];
#pragma unroll
        for (int i = 0; i < 4; ++i)
            af[i] = *(const bf16x8*)(lds_a + (wm * 64 + i * 16 + (lane & 15)) * 32 + (lane >> 4) * 8);
#pragma unroll
        for (int j = 0; j < 4; ++j)
            bfr[j] = *(const bf16x8*)(lds_b + (wn * 64 + j * 16 + (lane & 15)) * 32 + (lane >> 4) * 8);
#pragma unroll
        for (int i = 0; i < 4; ++i)
#pragma unroll
            for (int j = 0; j < 4; ++j)
                acc[i][j] = __builtin_amdgcn_mfma_f32_16x16x32_bf16(af[i], bfr[j], acc[i][j], 0, 0, 0);
        __syncthreads();
    }

    const float QSC = 0.18033688011112042f;  // log2(e) / sqrt(64)
    int t = n0 >> 10;  // 0=Q 1=K 2=V
#pragma unroll
    for (int j = 0; j < 4; ++j) {
        int col = n0 + wn * 64 + j * 16 + (lane & 15);
        float bias = biasf[col];
        int d  = col & 1023;
        int h  = d >> 6;
        int dk = d & 63;
#pragma unroll
        for (int i = 0; i < 4; ++i) {
#pragma unroll
            for (int r = 0; r < 4; ++r) {
                int row = m0 + wm * 64 + i * 16 + (lane >> 4) * 4 + r;
                float v = acc[i][j][r] + bias;
                if (t == 0) v *= QSC;            // uniform per block
                unsigned short bv16 = f2bf(v);
                int b_ = row >> 11, s_ = row & 2047;
                int bh = b_ * NHEAD + h;
                if (t == 0)      qb[((size_t)bh * SEQ + s_) * DKH + dk] = bv16;
                else if (t == 1) kb[((size_t)bh * SEQ + s_) * DKH + dk] = bv16;
                else             vtb[((size_t)bh * DKH + dk) * SEQ + s_] = bv16;
            }
        }
    }
}

// ---------------------------------------------------------------------------
// Kernel 3: flash attention, no-max unnormalized softmax.
//   S^T = mfma(K, Qscaled); P = v_exp_f32(S^T); PV direct from registers.
//   K: GLL-staged with 16B-chunk XOR swizzle (b128 reads, conflict-free).
//   V: reg-staged (T14 split: load early / ds_write late) with 8B-chunk XOR
//      swizzle pos8 = c8 ^ (d&15) -> PV b64 reads have bank = 2*((jb*4+g)^lq),
//      a bijection over lq per 16-lane phase => 0 conflicts (was +4 cyc/read).
//   Single barrier per kv-tile (V writes go to the not-being-read buffer).
// ---------------------------------------------------------------------------
__device__ __forceinline__ void stage_k(
    const unsigned short* __restrict__ kb,
    unsigned short* lk, int bh, int t, int wid, int srow8, int sc)
{
#pragma unroll
    for (int i = 0; i < 2; ++i) {
        int rb = wid * 16 + i * 8;
        int row = rb + srow8;
        int cs = (sc ^ (row & 7)) * 8;   // inverse-swizzled global source chunk
        GLL(kb + ((size_t)bh * SEQ + t * 64 + row) * DKH + cs, lk + rb * 64);
    }
}

__device__ __forceinline__ void vload(
    const unsigned short* __restrict__ vtb, int bh, int t, int vrow, int vseg,
    int4v& r0, int4v& r1)
{
    const unsigned short* p = vtb + ((size_t)bh * DKH + vrow) * SEQ + t * 64 + vseg * 16;
    r0 = *(const int4v*)(p);
    r1 = *(const int4v*)(p + 8);
}

__device__ __forceinline__ void vwrite(
    unsigned short* lv, int vrow, int vseg, const int4v& r0, const int4v& r1)
{
    int rx = vrow & 15;
    unsigned short* base = lv + vrow * 64;
    *(int2v*)(base + (((vseg * 4 + 0) ^ rx) * 4)) = (int2v){ r0[0], r0[1] };
    *(int2v*)(base + (((vseg * 4 + 1) ^ rx) * 4)) = (int2v){ r0[2], r0[3] };
    *(int2v*)(base + (((vseg * 4 + 2) ^ rx) * 4)) = (int2v){ r1[0], r1[1] };
    *(int2v*)(base + (((vseg * 4 + 3) ^ rx) * 4)) = (int2v){ r1[2], r1[3] };
}

__global__ __launch_bounds__(256) void k_attn(
    const unsigned short* __restrict__ qg,
    const unsigned short* __restrict__ kb,
    const unsigned short* __restrict__ vtb,
    unsigned short* __restrict__ ctxb)
{
    __shared__ unsigned short lds_k[2][64 * 64];
    __shared__ unsigned short lds_v[2][64 * 64];

    int bid = blockIdx.x;
    // XCD-grouped swizzle: all 16 q-tiles of a (b,h) land on the same XCD.
    int x = bid & 7, li = bid >> 3;
    int bh = x * 8 + (li >> 4);
    int qt = li & 15;

    int tid = threadIdx.x, wid = tid >> 6, lane = tid & 63;
    int lq = lane & 15, g = lane >> 4;
    int srow8 = lane >> 3, sc = lane & 7;
    int vrow = wid * 16 + (lane >> 2), vseg = lane & 3;

    // Q fragments: 2 q-sub-blocks x 2 k-halves, kept in registers
    bf16x8 aq[2][2];
    {
        const unsigned short* qp = qg + ((size_t)bh * SEQ + qt * 128 + wid * 32 + lq) * DKH + g * 8;
        aq[0][0] = *(const bf16x8*)(qp);
        aq[0][1] = *(const bf16x8*)(qp + 32);
        aq[1][0] = *(const bf16x8*)(qp + 16 * DKH);
        aq[1][1] = *(const bf16x8*)(qp + 16 * DKH + 32);
    }

    float lsum[2] = { 0.f, 0.f };
    f32x4 oacc[2][4] = {};   // O^T layout: row d = 4g+r (per dj block), col q = lq

    int4v vr0, vr1;

    // prologue: stage tile 0
    stage_k(kb, &lds_k[0][0], bh, 0, wid, srow8, sc);
    vload(vtb, bh, 0, vrow, vseg, vr0, vr1);
    asm volatile("s_waitcnt vmcnt(0)" ::: "memory");
    vwrite(&lds_v[0][0], vrow, vseg, vr0, vr1);
    asm volatile("s_waitcnt lgkmcnt(0)" ::: "memory");
    __builtin_amdgcn_sched_barrier(0);
    __builtin_amdgcn_s_barrier();

    for (int kt = 0; kt < 32; ++kt) {
        int cur = kt & 1;
        if (kt < 31) {
            stage_k(kb, &lds_k[cur ^ 1][0], bh, kt + 1, wid, srow8, sc);
            vload(vtb, bh, kt + 1, vrow, vseg, vr0, vr1);
        }

        // ---- S^T = K Q^T : cols = q-row (lq), rows = kv jb*16 + 4g+r ----
        f32x4 st[2][4] = {};
        __builtin_amdgcn_s_setprio(1);
#pragma unroll
        for (int kk = 0; kk < 2; ++kk) {
            bf16x8 kf[4];
#pragma unroll
            for (int jb = 0; jb < 4; ++jb) {
                int row = jb * 16 + lq;
                int c = kk * 4 + g;
                kf[jb] = *(const bf16x8*)(&lds_k[cur][row * 64 + ((c ^ (row & 7)) * 8)]);
            }
#pragma unroll
            for (int jb = 0; jb < 4; ++jb)
#pragma unroll
                for (int q = 0; q < 2; ++q)
                    st[q][jb] = __builtin_amdgcn_mfma_f32_16x16x32_bf16(kf[jb], aq[q][kk], st[q][jb], 0, 0, 0);
        }
        __builtin_amdgcn_s_setprio(0);

        // ---- P = 2^(S^T) unnormalized; lsum per-lane; pack B-frags ----
        short4v w[2][4];
#pragma unroll
        for (int q = 0; q < 2; ++q) {
#pragma unroll
            for (int jb = 0; jb < 4; ++jb) {
                float p0 = __builtin_amdgcn_exp2f(st[q][jb][0]);
                float p1 = __builtin_amdgcn_exp2f(st[q][jb][1]);
                float p2 = __builtin_amdgcn_exp2f(st[q][jb][2]);
                float p3 = __builtin_amdgcn_exp2f(st[q][jb][3]);
                lsum[q] += (p0 + p1) + (p2 + p3);
                bf16x4v pb;
                pb[0] = (__bf16)p0; pb[1] = (__bf16)p1; pb[2] = (__bf16)p2; pb[3] = (__bf16)p3;
                w[q][jb] = __builtin_bit_cast(short4v, pb);
            }
        }

        // ---- O^T += V^T @ P  (16x16x16, B-frag = P C-layout, no exchange) ----
        __builtin_amdgcn_s_setprio(1);
#pragma unroll
        for (int dj = 0; dj < 4; ++dj) {
            int rbase = (dj * 16 + lq) * 64;
#pragma unroll
            for (int jb = 0; jb < 4; ++jb) {
                short4v vf = *(const short4v*)(&lds_v[cur][rbase + (((jb * 4 + g) ^ lq) * 4)]);
#pragma unroll
                for (int q = 0; q < 2; ++q)
                    oacc[q][dj] = __builtin_amdgcn_mfma_f32_16x16x16bf16_1k(vf, w[q][jb], oacc[q][dj], 0, 0, 0);
            }
        }
        __builtin_amdgcn_s_setprio(0);

        // ---- late half of the V stage: drain loads, write NEXT buffer ----
        if (kt < 31) {
            asm volatile("s_waitcnt vmcnt(0)" ::: "memory");
            vwrite(&lds_v[cur ^ 1][0], vrow, vseg, vr0, vr1);
        }
        asm volatile("s_waitcnt lgkmcnt(0)" ::: "memory");
        __builtin_amdgcn_sched_barrier(0);
        __builtin_amdgcn_s_barrier();
    }

    // ---- epilogue: reduce lsum across g-groups, write ctx[b,s,h,dk] ----
    int b_ = bh >> 4, h = bh & 15;
#pragma unroll
    for (int q = 0; q < 2; ++q) {
        float s = lsum[q];
        s += __shfl_xor(s, 16);
        s += __shfl_xor(s, 32);
        float inv = 1.0f / s;
        int s_ = qt * 128 + wid * 32 + q * 16 + lq;
        unsigned short* op = ctxb + (((size_t)b_ * SEQ + s_) * NHEAD + h) * DKH;
#pragma unroll
        for (int dj = 0; dj < 4; ++dj) {
#pragma unroll
            for (int t = 0; t < 2; ++t) {
                unsigned short e0 = f2bf(oacc[q][dj][2 * t]     * inv);
                unsigned short e1 = f2bf(oacc[q][dj][2 * t + 1] * inv);
                unsigned int u = ((unsigned int)e1 << 16) | (unsigned int)e0;
                *(unsigned int*)(op + dj * 16 + 4 * g + 2 * t) = u;
            }
        }
    }
}

// ---------------------------------------------------------------------------
// Kernel 4: output projection  out[8192,1024] = ctxb * wob^T + bo  (fp32 out)
// ---------------------------------------------------------------------------
__global__ __launch_bounds__(256) void k_gemm_out(
    const unsigned short* __restrict__ A,    // ctxb [8192][1024] bf16
    const unsigned short* __restrict__ Bw,   // wob  [1024][1024] bf16
    const float* __restrict__ bo,
    float* __restrict__ out)
{
    __shared__ unsigned short lds_a[128 * 32];
    __shared__ unsigned short lds_b[128 * 32];

    const int NT = 1024 / 128;  // 8
    int bid = blockIdx.x;
    int tn = bid % NT, tm = bid / NT;
    int m0 = tm * 128, n0 = tn * 128;
    int tid = threadIdx.x, wid = tid >> 6, lane = tid & 63;
    int wm = wid >> 1, wn = wid & 1;

    f32x4 acc[4][4] = {};

    int srow = lane >> 2;
    int scol = (lane & 3) * 8;

    for (int kt = 0; kt < 32; ++kt) {
        int k0 = kt * 32;
#pragma unroll
        for (int i = 0; i < 2; ++i) {
            int rb = (wid * 2 + i) * 16;
            GLL(A  + (size_t)(m0 + rb + srow) * 1024 + k0 + scol, lds_a + rb * 32);
            GLL(Bw + (size_t)(n0 + rb + srow) * 1024 + k0 + scol, lds_b + rb * 32);
        }
        __syncthreads();
        bf16x8 af[4], bfr[4];
#pragma unroll
        for (int i = 0; i < 4; ++i)
            af[i] = *(const bf16x8*)(lds_a + (wm * 64 + i * 16 + (lane & 15)) * 32 + (lane >> 4) * 8);
#pragma unroll
        for (int j = 0; j < 4; ++j)
            bfr[j] = *(const bf16x8*)(lds_b + (wn * 64 + j * 16 + (lane & 15)) * 32 + (lane >> 4) * 8);
#pragma unroll
        for (int i = 0; i < 4; ++i)
#pragma unroll
            for (int j = 0; j < 4; ++j)
                acc[i][j] = __builtin_amdgcn_mfma_f32_16x16x32_bf16(af[i], bfr[j], acc[i][j], 0, 0, 0);
        __syncthreads();
    }

#pragma unroll
    for (int j = 0; j < 4; ++j) {
        int col = n0 + wn * 64 + j * 16 + (lane & 15);
        float bias = bo[col];
#pragma unroll
        for (int i = 0; i < 4; ++i) {
#pragma unroll
            for (int r = 0; r < 4; ++r) {
                int row = m0 + wm * 64 + i * 16 + (lane >> 4) * 4 + r;
                out[(size_t)row * 1024 + col] = acc[i][j][r] + bias;
            }
        }
    }
}

// ---------------------------------------------------------------------------
extern "C" void kernel_launch(void* const* d_in, const int* in_sizes, int n_in,
                              void* d_out, int out_size, void* d_ws, size_t ws_size,
                              hipStream_t stream)
{
    const float* z  = (const float*)d_in[0];
    const float* Wq = (const float*)d_in[1];
    const float* bq = (const float*)d_in[2];
    const float* Wk = (const float*)d_in[3];
    const float* bk = (const float*)d_in[4];
    const float* Wv = (const float*)d_in[5];
    const float* bv = (const float*)d_in[6];
    const float* Wo = (const float*)d_in[7];
    const float* bo = (const float*)d_in[8];
    float* out = (float*)d_out;

    char* ws = (char*)d_ws;
    unsigned short* zb   = (unsigned short*)(ws);                        // 16 MB
    unsigned short* ctxb = (unsigned short*)(ws);                        // 16 MB (reuse)
    unsigned short* wqkv = (unsigned short*)(ws + (16ull << 20));        //  6 MB
    unsigned short* wob  = (unsigned short*)(ws + (22ull << 20));        //  2 MB
    float*          biasf= (float*)(ws + (24ull << 20));                 // 12 KB
    unsigned short* qb   = (unsigned short*)(ws + (25ull << 20));        // 16 MB
    unsigned short* kb   = (unsigned short*)(ws + (41ull << 20));        // 16 MB
    unsigned short* vtb  = (unsigned short*)(ws + (57ull << 20));        // 16 MB -> 73 MB total

    k_convert<<<8192, 256, 0, stream>>>(z, Wq, Wk, Wv, Wo, bq, bk, bv, zb, wqkv, wob, biasf);
    k_gemm_qkv<<<64 * 24, 256, 0, stream>>>(zb, wqkv, biasf, qb, kb, vtb);
    k_attn<<<NBH * 16, 256, 0, stream>>>(qb, kb, vtb, ctxb);
    k_gemm_out<<<64 * 8, 256, 0, stream>>>(ctxb, wob, bo, out);
}

// Round 6
// 238.661 us; speedup vs baseline: 1.1179x; 1.0029x over previous
//
#include <hip/hip_runtime.h>
#include <stdint.h>

#define D_MODEL 1024
#define NHEAD 16
#define DKH 64
#define BATCH 4
#define SEQ 2048
#define M_ROWS (BATCH*SEQ)   // 8192
#define NBH (BATCH*NHEAD)    // 64

typedef float f32x4 __attribute__((ext_vector_type(4)));
typedef __bf16 bf16x8 __attribute__((ext_vector_type(8)));
typedef __bf16 bf16x4v __attribute__((ext_vector_type(4)));
typedef short short4v __attribute__((ext_vector_type(4)));
typedef int int2v __attribute__((ext_vector_type(2)));
typedef int int4v __attribute__((ext_vector_type(4)));

__device__ __forceinline__ unsigned short f2bf(float x) {
    __bf16 b = (__bf16)x;                      // hardware v_cvt (RNE)
    return __builtin_bit_cast(unsigned short, b);
}

#define GLL(gsrc, ldst) \
    __builtin_amdgcn_global_load_lds((const __attribute__((address_space(1))) void*)(gsrc), \
                                     (__attribute__((address_space(3))) void*)(ldst), 16, 0, 0)

// ---------------------------------------------------------------------------
// Kernel 1: fp32 -> bf16 conversion / packing
// ---------------------------------------------------------------------------
__global__ __launch_bounds__(256) void k_convert(
    const float* __restrict__ z,  const float* __restrict__ wq,
    const float* __restrict__ wk, const float* __restrict__ wv,
    const float* __restrict__ wo,
    const float* __restrict__ bq, const float* __restrict__ bk,
    const float* __restrict__ bv,
    unsigned short* __restrict__ zb, unsigned short* __restrict__ wqkv,
    unsigned short* __restrict__ wob, float* __restrict__ biasf)
{
    int i = blockIdx.x * 256 + threadIdx.x;   // 0 .. 2097151
    {
        float4 v = ((const float4*)z)[i];
        ushort4 o; o.x = f2bf(v.x); o.y = f2bf(v.y); o.z = f2bf(v.z); o.w = f2bf(v.w);
        ((ushort4*)zb)[i] = o;
    }
    if (i < 262144) {   // 1048576/4 per weight matrix
        float4 v;
        ushort4 o;
        v = ((const float4*)wq)[i];
        o.x=f2bf(v.x); o.y=f2bf(v.y); o.z=f2bf(v.z); o.w=f2bf(v.w);
        ((ushort4*)wqkv)[i] = o;
        v = ((const float4*)wk)[i];
        o.x=f2bf(v.x); o.y=f2bf(v.y); o.z=f2bf(v.z); o.w=f2bf(v.w);
        ((ushort4*)wqkv)[262144 + i] = o;
        v = ((const float4*)wv)[i];
        o.x=f2bf(v.x); o.y=f2bf(v.y); o.z=f2bf(v.z); o.w=f2bf(v.w);
        ((ushort4*)wqkv)[524288 + i] = o;
        v = ((const float4*)wo)[i];
        o.x=f2bf(v.x); o.y=f2bf(v.y); o.z=f2bf(v.z); o.w=f2bf(v.w);
        ((ushort4*)wob)[i] = o;
    }
    if (i < 1024) {
        biasf[i]        = bq[i];
        biasf[1024 + i] = bk[i];
        biasf[2048 + i] = bv[i];
    }
}

// ---------------------------------------------------------------------------
// Kernel 2: QKV projection GEMM  C[8192,3072] = zb * wqkv^T + bias
// Q is pre-scaled by log2(e)/8 (softmax scale folded, log2 domain) so the
// attention kernel can use raw v_exp_f32 (2^x) with no per-element mul/sub.
// ---------------------------------------------------------------------------
__global__ __launch_bounds__(256) void k_gemm_qkv(
    const unsigned short* __restrict__ A,   // [8192][1024] bf16
    const unsigned short* __restrict__ Bw,  // [3072][1024] bf16
    const float* __restrict__ biasf,        // [3072]
    unsigned short* __restrict__ qb, unsigned short* __restrict__ kb,
    unsigned short* __restrict__ vtb)
{
    __shared__ unsigned short lds_a[128 * 32];
    __shared__ unsigned short lds_b[128 * 32];

    const int NT = 3072 / 128;  // 24
    int bid = blockIdx.x;
    int tn = bid % NT, tm = bid / NT;
    int m0 = tm * 128, n0 = tn * 128;
    int tid = threadIdx.x, wid = tid >> 6, lane = tid & 63;
    int wm = wid >> 1, wn = wid & 1;

    f32x4 acc[4][4] = {};

    int srow = lane >> 2;        // 0..15
    int scol = (lane & 3) * 8;   // element offset within 32-col row

    for (int kt = 0; kt < 32; ++kt) {
        int k0 = kt * 32;
#pragma unroll
        for (int i = 0; i < 2; ++i) {
            int rb = (wid * 2 + i) * 16;
            GLL(A  + (size_t)(m0 + rb + srow) * 1024 + k0 + scol, lds_a + rb * 32);
            GLL(Bw + (size_t)(n0 + rb + srow) * 1024 + k0 + scol, lds_b + rb * 32);
        }
        __syncthreads();
        bf16x8 af[4], bfr[4];
#pragma unroll
        for (int i = 0; i < 4; ++i)
            af[i] = *(const bf16x8*)(lds_a + (wm * 64 + i * 16 + (lane & 15)) * 32 + (lane >> 4) * 8);
#pragma unroll
        for (int j = 0; j < 4; ++j)
            bfr[j] = *(const bf16x8*)(lds_b + (wn * 64 + j * 16 + (lane & 15)) * 32 + (lane >> 4) * 8);
#pragma unroll
        for (int i = 0; i < 4; ++i)
#pragma unroll
            for (int j = 0; j < 4; ++j)
                acc[i][j] = __builtin_amdgcn_mfma_f32_16x16x32_bf16(af[i], bfr[j], acc[i][j], 0, 0, 0);
        __syncthreads();
    }

    const float QSC = 0.18033688011112042f;  // log2(e) / sqrt(64)
    int t = n0 >> 10;  // 0=Q 1=K 2=V
#pragma unroll
    for (int j = 0; j < 4; ++j) {
        int col = n0 + wn * 64 + j * 16 + (lane & 15);
        float bias = biasf[col];
        int d  = col & 1023;
        int h  = d >> 6;
        int dk = d & 63;
#pragma unroll
        for (int i = 0; i < 4; ++i) {
#pragma unroll
            for (int r = 0; r < 4; ++r) {
                int row = m0 + wm * 64 + i * 16 + (lane >> 4) * 4 + r;
                float v = acc[i][j][r] + bias;
                if (t == 0) v *= QSC;            // uniform per block
                unsigned short bv16 = f2bf(v);
                int b_ = row >> 11, s_ = row & 2047;
                int bh = b_ * NHEAD + h;
                if (t == 0)      qb[((size_t)bh * SEQ + s_) * DKH + dk] = bv16;
                else if (t == 1) kb[((size_t)bh * SEQ + s_) * DKH + dk] = bv16;
                else             vtb[((size_t)bh * DKH + dk) * SEQ + s_] = bv16;
            }
        }
    }
}

// ---------------------------------------------------------------------------
// Kernel 3: flash attention, no-max unnormalized softmax, 2-deep K pipeline.
//   S^T = mfma(K, Qscaled); P = v_exp_f32(S^T); PV direct from registers.
//   K: GLL-staged into a 3-slot LDS rotation; GLLs for kt+2 issued at top of
//      kt and left IN FLIGHT across the barrier (bottom wait = vmcnt(2), never
//      0 in steady state) -> K latency budget ~2 iterations.
//   V: reg-staged (load top / ds_write bottom) with 8B-chunk XOR swizzle
//      (0 bank conflicts, verified R5). vload issued BEFORE GLLs so vmcnt(2)
//      retires exactly {K[kt+1], V[kt+1]-regs} and leaves K[kt+2] flying.
// ---------------------------------------------------------------------------
__device__ __forceinline__ void stage_k(
    const unsigned short* __restrict__ kb,
    unsigned short* lk, int bh, int t, int wid, int srow8, int sc)
{
#pragma unroll
    for (int i = 0; i < 2; ++i) {
        int rb = wid * 16 + i * 8;
        int row = rb + srow8;
        int cs = (sc ^ (row & 7)) * 8;   // inverse-swizzled global source chunk
        GLL(kb + ((size_t)bh * SEQ + t * 64 + row) * DKH + cs, lk + rb * 64);
    }
}

__device__ __forceinline__ void vload(
    const unsigned short* __restrict__ vtb, int bh, int t, int vrow, int vseg,
    int4v& r0, int4v& r1)
{
    const unsigned short* p = vtb + ((size_t)bh * DKH + vrow) * SEQ + t * 64 + vseg * 16;
    r0 = *(const int4v*)(p);
    r1 = *(const int4v*)(p + 8);
}

__device__ __forceinline__ void vwrite(
    unsigned short* lv, int vrow, int vseg, const int4v& r0, const int4v& r1)
{
    int rx = vrow & 15;
    unsigned short* base = lv + vrow * 64;
    *(int2v*)(base + (((vseg * 4 + 0) ^ rx) * 4)) = (int2v){ r0[0], r0[1] };
    *(int2v*)(base + (((vseg * 4 + 1) ^ rx) * 4)) = (int2v){ r0[2], r0[3] };
    *(int2v*)(base + (((vseg * 4 + 2) ^ rx) * 4)) = (int2v){ r1[0], r1[1] };
    *(int2v*)(base + (((vseg * 4 + 3) ^ rx) * 4)) = (int2v){ r1[2], r1[3] };
}

__global__ __launch_bounds__(256) void k_attn(
    const unsigned short* __restrict__ qg,
    const unsigned short* __restrict__ kb,
    const unsigned short* __restrict__ vtb,
    unsigned short* __restrict__ ctxb)
{
    __shared__ unsigned short lds_k[3][64 * 64];
    __shared__ unsigned short lds_v[2][64 * 64];

    int bid = blockIdx.x;
    // XCD-grouped swizzle: all 16 q-tiles of a (b,h) land on the same XCD.
    int x = bid & 7, li = bid >> 3;
    int bh = x * 8 + (li >> 4);
    int qt = li & 15;

    int tid = threadIdx.x, wid = tid >> 6, lane = tid & 63;
    int lq = lane & 15, g = lane >> 4;
    int srow8 = lane >> 3, sc = lane & 7;
    int vrow = wid * 16 + (lane >> 2), vseg = lane & 3;

    // Q fragments: 2 q-sub-blocks x 2 k-halves, kept in registers
    bf16x8 aq[2][2];
    {
        const unsigned short* qp = qg + ((size_t)bh * SEQ + qt * 128 + wid * 32 + lq) * DKH + g * 8;
        aq[0][0] = *(const bf16x8*)(qp);
        aq[0][1] = *(const bf16x8*)(qp + 32);
        aq[1][0] = *(const bf16x8*)(qp + 16 * DKH);
        aq[1][1] = *(const bf16x8*)(qp + 16 * DKH + 32);
    }

    float lsum[2] = { 0.f, 0.f };
    f32x4 oacc[2][4] = {};   // O^T layout: row d = 4g+r (per dj block), col q = lq

    int4v vr0, vr1;

    // ---- prologue: V0 regs + K0 + K1 staged; K1 may stay in flight ----
    vload(vtb, bh, 0, vrow, vseg, vr0, vr1);       // q: vl,vl
    stage_k(kb, &lds_k[0][0], bh, 0, wid, srow8, sc);   // q: vl,vl,g0,g0
    stage_k(kb, &lds_k[1][0], bh, 1, wid, srow8, sc);   // q: vl,vl,g0,g0,g1,g1
    asm volatile("s_waitcnt vmcnt(4)" ::: "memory");    // V0 regs done
    vwrite(&lds_v[0][0], vrow, vseg, vr0, vr1);
    asm volatile("s_waitcnt vmcnt(2)" ::: "memory");    // K0 done (K1 flying)
    asm volatile("s_waitcnt lgkmcnt(0)" ::: "memory");  // V0 written
    __builtin_amdgcn_sched_barrier(0);
    __builtin_amdgcn_s_barrier();

    for (int kt = 0; kt < 32; ++kt) {
        int kc = kt % 3;         // K slot being consumed
        int vcur = kt & 1;       // V slot being consumed

        // issue next-tile loads: vload FIRST (so vmcnt(2) retires it), GLL second
        if (kt < 31) vload(vtb, bh, kt + 1, vrow, vseg, vr0, vr1);
        if (kt < 30) stage_k(kb, &lds_k[(kt + 2) % 3][0], bh, kt + 2, wid, srow8, sc);

        // ---- S^T = K Q^T : cols = q-row (lq), rows = kv jb*16 + 4g+r ----
        f32x4 st[2][4] = {};
        __builtin_amdgcn_s_setprio(1);
#pragma unroll
        for (int kk = 0; kk < 2; ++kk) {
            bf16x8 kf[4];
#pragma unroll
            for (int jb = 0; jb < 4; ++jb) {
                int row = jb * 16 + lq;
                int c = kk * 4 + g;
                kf[jb] = *(const bf16x8*)(&lds_k[kc][row * 64 + ((c ^ (row & 7)) * 8)]);
            }
#pragma unroll
            for (int jb = 0; jb < 4; ++jb)
#pragma unroll
                for (int q = 0; q < 2; ++q)
                    st[q][jb] = __builtin_amdgcn_mfma_f32_16x16x32_bf16(kf[jb], aq[q][kk], st[q][jb], 0, 0, 0);
        }
        __builtin_amdgcn_s_setprio(0);

        // ---- P = 2^(S^T) unnormalized; lsum per-lane; pack B-frags ----
        short4v w[2][4];
#pragma unroll
        for (int q = 0; q < 2; ++q) {
#pragma unroll
            for (int jb = 0; jb < 4; ++jb) {
                float p0 = __builtin_amdgcn_exp2f(st[q][jb][0]);
                float p1 = __builtin_amdgcn_exp2f(st[q][jb][1]);
                float p2 = __builtin_amdgcn_exp2f(st[q][jb][2]);
                float p3 = __builtin_amdgcn_exp2f(st[q][jb][3]);
                lsum[q] += (p0 + p1) + (p2 + p3);
                bf16x4v pb;
                pb[0] = (__bf16)p0; pb[1] = (__bf16)p1; pb[2] = (__bf16)p2; pb[3] = (__bf16)p3;
                w[q][jb] = __builtin_bit_cast(short4v, pb);
            }
        }

        // ---- O^T += V^T @ P  (16x16x16, B-frag = P C-layout, no exchange) ----
        __builtin_amdgcn_s_setprio(1);
#pragma unroll
        for (int dj = 0; dj < 4; ++dj) {
            int rbase = (dj * 16 + lq) * 64;
#pragma unroll
            for (int jb = 0; jb < 4; ++jb) {
                short4v vf = *(const short4v*)(&lds_v[vcur][rbase + (((jb * 4 + g) ^ lq) * 4)]);
#pragma unroll
                for (int q = 0; q < 2; ++q)
                    oacc[q][dj] = __builtin_amdgcn_mfma_f32_16x16x16bf16_1k(vf, w[q][jb], oacc[q][dj], 0, 0, 0);
            }
        }
        __builtin_amdgcn_s_setprio(0);

        // ---- bottom: counted drain (K[kt+2] stays in flight), write V ----
        if (kt < 30) {
            asm volatile("s_waitcnt vmcnt(2)" ::: "memory");   // K[kt+1]+V-regs done
            vwrite(&lds_v[vcur ^ 1][0], vrow, vseg, vr0, vr1);
            asm volatile("s_waitcnt lgkmcnt(0)" ::: "memory");
            __builtin_amdgcn_sched_barrier(0);
            __builtin_amdgcn_s_barrier();
        } else if (kt == 30) {
            asm volatile("s_waitcnt vmcnt(0)" ::: "memory");   // tail: drain all
            vwrite(&lds_v[vcur ^ 1][0], vrow, vseg, vr0, vr1);
            asm volatile("s_waitcnt lgkmcnt(0)" ::: "memory");
            __builtin_amdgcn_sched_barrier(0);
            __builtin_amdgcn_s_barrier();
        }
    }

    // ---- epilogue: reduce lsum across g-groups, write ctx[b,s,h,dk] ----
    int b_ = bh >> 4, h = bh & 15;
#pragma unroll
    for (int q = 0; q < 2; ++q) {
        float s = lsum[q];
        s += __shfl_xor(s, 16);
        s += __shfl_xor(s, 32);
        float inv = 1.0f / s;
        int s_ = qt * 128 + wid * 32 + q * 16 + lq;
        unsigned short* op = ctxb + (((size_t)b_ * SEQ + s_) * NHEAD + h) * DKH;
#pragma unroll
        for (int dj = 0; dj < 4; ++dj) {
#pragma unroll
            for (int t = 0; t < 2; ++t) {
                unsigned short e0 = f2bf(oacc[q][dj][2 * t]     * inv);
                unsigned short e1 = f2bf(oacc[q][dj][2 * t + 1] * inv);
                unsigned int u = ((unsigned int)e1 << 16) | (unsigned int)e0;
                *(unsigned int*)(op + dj * 16 + 4 * g + 2 * t) = u;
            }
        }
    }
}

// ---------------------------------------------------------------------------
// Kernel 4: output projection  out[8192,1024] = ctxb * wob^T + bo  (fp32 out)
// ---------------------------------------------------------------------------
__global__ __launch_bounds__(256) void k_gemm_out(
    const unsigned short* __restrict__ A,    // ctxb [8192][1024] bf16
    const unsigned short* __restrict__ Bw,   // wob  [1024][1024] bf16
    const float* __restrict__ bo,
    float* __restrict__ out)
{
    __shared__ unsigned short lds_a[128 * 32];
    __shared__ unsigned short lds_b[128 * 32];

    const int NT = 1024 / 128;  // 8
    int bid = blockIdx.x;
    int tn = bid % NT, tm = bid / NT;
    int m0 = tm * 128, n0 = tn * 128;
    int tid = threadIdx.x, wid = tid >> 6, lane = tid & 63;
    int wm = wid >> 1, wn = wid & 1;

    f32x4 acc[4][4] = {};

    int srow = lane >> 2;
    int scol = (lane & 3) * 8;

    for (int kt = 0; kt < 32; ++kt) {
        int k0 = kt * 32;
#pragma unroll
        for (int i = 0; i < 2; ++i) {
            int rb = (wid * 2 + i) * 16;
            GLL(A  + (size_t)(m0 + rb + srow) * 1024 + k0 + scol, lds_a + rb * 32);
            GLL(Bw + (size_t)(n0 + rb + srow) * 1024 + k0 + scol, lds_b + rb * 32);
        }
        __syncthreads();
        bf16x8 af[4], bfr[4];
#pragma unroll
        for (int i = 0; i < 4; ++i)
            af[i] = *(const bf16x8*)(lds_a + (wm * 64 + i * 16 + (lane & 15)) * 32 + (lane >> 4) * 8);
#pragma unroll
        for (int j = 0; j < 4; ++j)
            bfr[j] = *(const bf16x8*)(lds_b + (wn * 64 + j * 16 + (lane & 15)) * 32 + (lane >> 4) * 8);
#pragma unroll
        for (int i = 0; i < 4; ++i)
#pragma unroll
            for (int j = 0; j < 4; ++j)
                acc[i][j] = __builtin_amdgcn_mfma_f32_16x16x32_bf16(af[i], bfr[j], acc[i][j], 0, 0, 0);
        __syncthreads();
    }

#pragma unroll
    for (int j = 0; j < 4; ++j) {
        int col = n0 + wn * 64 + j * 16 + (lane & 15);
        float bias = bo[col];
#pragma unroll
        for (int i = 0; i < 4; ++i) {
#pragma unroll
            for (int r = 0; r < 4; ++r) {
                int row = m0 + wm * 64 + i * 16 + (lane >> 4) * 4 + r;
                out[(size_t)row * 1024 + col] = acc[i][j][r] + bias;
            }
        }
    }
}

// ---------------------------------------------------------------------------
extern "C" void kernel_launch(void* const* d_in, const int* in_sizes, int n_in,
                              void* d_out, int out_size, void* d_ws, size_t ws_size,
                              hipStream_t stream)
{
    const float* z  = (const float*)d_in[0];
    const float* Wq = (const float*)d_in[1];
    const float* bq = (const float*)d_in[2];
    const float* Wk = (const float*)d_in[3];
    const float* bk = (const float*)d_in[4];
    const float* Wv = (const float*)d_in[5];
    const float* bv = (const float*)d_in[6];
    const float* Wo = (const float*)d_in[7];
    const float* bo = (const float*)d_in[8];
    float* out = (float*)d_out;

    char* ws = (char*)d_ws;
    unsigned short* zb   = (unsigned short*)(ws);                        // 16 MB
    unsigned short* ctxb = (unsigned short*)(ws);                        // 16 MB (reuse)
    unsigned short* wqkv = (unsigned short*)(ws + (16ull << 20));        //  6 MB
    unsigned short* wob  = (unsigned short*)(ws + (22ull << 20));        //  2 MB
    float*          biasf= (float*)(ws + (24ull << 20));                 // 12 KB
    unsigned short* qb   = (unsigned short*)(ws + (25ull << 20));        // 16 MB
    unsigned short* kb   = (unsigned short*)(ws + (41ull << 20));        // 16 MB
    unsigned short* vtb  = (unsigned short*)(ws + (57ull << 20));        // 16 MB -> 73 MB total

    k_convert<<<8192, 256, 0, stream>>>(z, Wq, Wk, Wv, Wo, bq, bk, bv, zb, wqkv, wob, biasf);
    k_gemm_qkv<<<64 * 24, 256, 0, stream>>>(zb, wqkv, biasf, qb, kb, vtb);
    k_attn<<<NBH * 16, 256, 0, stream>>>(qb, kb, vtb, ctxb);
    k_gemm_out<<<64 * 8, 256, 0, stream>>>(ctxb, wob, bo, out);
}